// Round 2
// baseline (195.864 us; speedup 1.0000x reference)
//
#include <hip/hip_runtime.h>
#include <math.h>

// Shapes: B=3200, L=7, H=8, E=64, S=56, D=64, N=50
// queries [B,7,8,64], keys [B,56,8,64], values [B,56,8,64], mask [50,7,56]
// out [B,7,8,64] fp32.
//
// 128-thread blocks = 2 independent waves, one (b,h) unit per wave.
// K staged half-at-a-time (56 x 128B) via global_load_lds with pre-swizzled
// per-lane global source (XOR swizzle -> conflict-free ds_read_b128, no pad,
// no staging VGPRs). P transposed through the dead K buffer. V streamed
// directly from global (read-once). Softmax normalization deferred to epilogue.

#define GLDS(gp, lp) __builtin_amdgcn_global_load_lds(                        \
    (const __attribute__((address_space(1))) void*)(gp),                      \
    (__attribute__((address_space(3))) void*)(lp), 16, 0, 0)

__launch_bounds__(128)
__global__ void fullattn_kernel(const float* __restrict__ q,
                                const float* __restrict__ k,
                                const float* __restrict__ v,
                                const float* __restrict__ mask,
                                float* __restrict__ out,
                                int nstations) {
    // per-wave half-K buffer: 56 rows x 8 float4 (swizzled), 7168 B each
    __shared__ __align__(16) float KL2[2][1792];

    const int lane = threadIdx.x & 63;
    const int wid  = threadIdx.x >> 6;
    const int unit = blockIdx.x * 2 + wid;
    const int b    = unit >> 3;
    const int h    = unit & 7;
    const int st   = b % nstations;

    float* KL = KL2[wid];

    const int kbase = b * 28672 + h * 64;  // keys/values: b*56*8*64 + h*64
    const int qbase = b * 3584  + h * 64;  // queries/out: b*7*8*64 + h*64

    // ---- mask rows (pre-scaled); clamp pad lanes ----
    const int ml = (lane < 56) ? lane : 55;
    float m[7];
#pragma unroll
    for (int l = 0; l < 7; ++l)
        m[l] = mask[st * 392 + l * 56 + ml] * 0.125f;  // scale = 1/sqrt(64)

    const int sc_row = (lane < 56) ? lane : 55;  // clamped K row for this lane
    const int sx     = sc_row & 7;               // XOR swizzle key
    const float* qp  = q + qbase;

    float acc[7];
#pragma unroll
    for (int l = 0; l < 7; ++l) acc[l] = 0.0f;

    // staging decode: slot f = i*64+lane -> row s=f>>3, chunk e4=(f&7)^(s&7)
#pragma unroll
    for (int half = 0; half < 2; ++half) {
        const int eoff = half * 32;  // float offset of this e-half
#pragma unroll
        for (int i = 0; i < 7; ++i) {
            const int f  = i * 64 + lane;
            const int s  = f >> 3;
            const int e4 = (f & 7) ^ (s & 7);
            GLDS(k + kbase + s * 512 + eoff + e4 * 4, (char*)KL + i * 1024);
        }
        asm volatile("s_waitcnt vmcnt(0)" ::: "memory");

#pragma unroll
        for (int ee = 0; ee < 8; ++ee) {
            const float4 kv = *(const float4*)(&KL[sc_row * 32 + ((ee ^ sx) << 2)]);
#pragma unroll
            for (int l = 0; l < 7; ++l) {
                // wave-uniform address -> scalar (s_load) path
                const float4 q4 = *(const float4*)(qp + l * 512 + eoff + ee * 4);
                acc[l] = fmaf(q4.x, kv.x, acc[l]);
                acc[l] = fmaf(q4.y, kv.y, acc[l]);
                acc[l] = fmaf(q4.z, kv.z, acc[l]);
                acc[l] = fmaf(q4.w, kv.w, acc[l]);
            }
        }
        // ensure this half's ds_reads delivered before next half's DMA lands
        asm volatile("s_waitcnt lgkmcnt(0)" ::: "memory");
    }

    // ---- softmax across lanes (s); write P transposed into dead K buffer ----
    float* pbuf = KL;
    float rdenom[7];
#pragma unroll
    for (int l = 0; l < 7; ++l) {
        float sc = acc[l] * m[l];
        if (lane >= 56) sc = -INFINITY;
        float mx = sc;
#pragma unroll
        for (int off = 32; off >= 1; off >>= 1)
            mx = fmaxf(mx, __shfl_xor(mx, off));
        const float p = __expf(sc - mx);   // pad lanes: exp(-inf)=0
        float sum = p;
#pragma unroll
        for (int off = 32; off >= 1; off >>= 1)
            sum += __shfl_xor(sum, off);
        pbuf[l * 64 + lane] = p;
        rdenom[l] = 1.0f / sum;
    }

    // ---- PV: lane = d, V rows streamed straight from global ----
    float facc[7];
#pragma unroll
    for (int l = 0; l < 7; ++l) facc[l] = 0.0f;

#pragma unroll
    for (int s4 = 0; s4 < 14; ++s4) {
        const float vr0 = v[kbase + (s4 * 4 + 0) * 512 + lane];
        const float vr1 = v[kbase + (s4 * 4 + 1) * 512 + lane];
        const float vr2 = v[kbase + (s4 * 4 + 2) * 512 + lane];
        const float vr3 = v[kbase + (s4 * 4 + 3) * 512 + lane];
#pragma unroll
        for (int l = 0; l < 7; ++l) {
            const float4 p4 = *(const float4*)(&pbuf[l * 64 + s4 * 4]);  // broadcast
            facc[l] = fmaf(p4.x, vr0, facc[l]);
            facc[l] = fmaf(p4.y, vr1, facc[l]);
            facc[l] = fmaf(p4.z, vr2, facc[l]);
            facc[l] = fmaf(p4.w, vr3, facc[l]);
        }
    }

    // ---- epilogue: deferred softmax normalization + coalesced store ----
#pragma unroll
    for (int l = 0; l < 7; ++l)
        out[qbase + l * 512 + lane] = facc[l] * rdenom[l];
}

extern "C" void kernel_launch(void* const* d_in, const int* in_sizes, int n_in,
                              void* d_out, int out_size, void* d_ws, size_t ws_size,
                              hipStream_t stream) {
    const float* q    = (const float*)d_in[0];
    const float* k    = (const float*)d_in[1];
    const float* v    = (const float*)d_in[2];
    const float* mask = (const float*)d_in[3];
    float* out        = (float*)d_out;

    const int B = in_sizes[0] / (7 * 8 * 64);        // 3200
    const int nstations = in_sizes[3] / (7 * 56);    // 50

    const int units = B * 8;                         // 25600
    fullattn_kernel<<<dim3(units / 2), dim3(128), 0, stream>>>(q, k, v, mask, out, nstations);
}

// Round 3
// 168.937 us; speedup vs baseline: 1.1594x; 1.1594x over previous
//
#include <hip/hip_runtime.h>
#include <math.h>

// Shapes: B=3200, L=7, H=8, E=64, S=56, D=64, N=50
// queries [B,7,8,64], keys [B,56,8,64], values [B,56,8,64], mask [50,7,56]
// out [B,7,8,64] fp32.
//
// One wave (64-thread block) per (b,h) unit -> Q addresses provably uniform
// (scalar path). K staged in LDS as fp16 (7168 B/wave, XOR-swizzled b128
// chunks, conflict-free, coalesced staging loads). V pipelined into registers
// in two 28-row chunks issued ahead of their consumers (hides HBM latency
// under softmax / PV compute). P transposed through the dead K buffer.
// Softmax normalization deferred to the epilogue.

typedef __attribute__((ext_vector_type(8))) _Float16 half8;

__launch_bounds__(64)
__global__ void fullattn_kernel(const float* __restrict__ q,
                                const float* __restrict__ k,
                                const float* __restrict__ v,
                                const float* __restrict__ mask,
                                float* __restrict__ out,
                                int nstations) {
    __shared__ __align__(16) _Float16 KL[56 * 64];  // 7168 B; P (fp32) overlays after scores

    const int lane = threadIdx.x;     // 0..63
    const int unit = blockIdx.x;
    const int b    = unit >> 3;
    const int h    = unit & 7;
    const int st   = b % nstations;

    const int kbase = b * 28672 + h * 64;  // keys/values: b*56*8*64 + h*64
    const int qbase = b * 3584  + h * 64;  // queries/out: b*7*8*64 + h*64

    // ---- mask rows (early issue, pre-scaled); clamp pad lanes ----
    const int ml = (lane < 56) ? lane : 55;
    float m[7];
#pragma unroll
    for (int l = 0; l < 7; ++l)
        m[l] = mask[st * 392 + l * 56 + ml] * 0.125f;  // scale = 1/sqrt(64)

    // ---- stage K -> LDS fp16, XOR-swizzled 16B chunks ----
    // slot f = i*64+lane: row s=f>>3, chunk c=f&7 (32B fp32 -> 16B fp16)
    // physical chunk slot = c ^ (s&7): conflict-free write AND read.
#pragma unroll
    for (int i = 0; i < 7; ++i) {
        const int f = i * 64 + lane;
        const int s = f >> 3;
        const int c = f & 7;
        const float4 a0 = *(const float4*)(k + kbase + s * 512 + c * 8);
        const float4 a1 = *(const float4*)(k + kbase + s * 512 + c * 8 + 4);
        half8 hv;
        hv[0] = (_Float16)a0.x; hv[1] = (_Float16)a0.y;
        hv[2] = (_Float16)a0.z; hv[3] = (_Float16)a0.w;
        hv[4] = (_Float16)a1.x; hv[5] = (_Float16)a1.y;
        hv[6] = (_Float16)a1.z; hv[7] = (_Float16)a1.w;
        *(half8*)(&KL[s * 64 + 8 * (c ^ (s & 7))]) = hv;
    }
    // single wave per block: DS pipe in-order, compiler inserts lgkmcnt.

    // ---- scores: lane = s, acc[l] = Q[l] . K[s] (Q via uniform scalar loads) ----
    const int sr = (lane < 56) ? lane : 55;
    const int sx = sr & 7;
    const float* qp = q + qbase;

    float acc[7];
#pragma unroll
    for (int l = 0; l < 7; ++l) acc[l] = 0.0f;

#pragma unroll
    for (int c = 0; c < 8; ++c) {
        const half8 kv = *(const half8*)(&KL[sr * 64 + 8 * (c ^ sx)]);
        float kf[8];
#pragma unroll
        for (int j = 0; j < 8; ++j) kf[j] = (float)kv[j];  // folds into v_fma_mix
#pragma unroll
        for (int l = 0; l < 7; ++l) {
            const float4 q0 = *(const float4*)(qp + l * 512 + c * 8);
            const float4 q1 = *(const float4*)(qp + l * 512 + c * 8 + 4);
            acc[l] = fmaf(q0.x, kf[0], acc[l]);
            acc[l] = fmaf(q0.y, kf[1], acc[l]);
            acc[l] = fmaf(q0.z, kf[2], acc[l]);
            acc[l] = fmaf(q0.w, kf[3], acc[l]);
            acc[l] = fmaf(q1.x, kf[4], acc[l]);
            acc[l] = fmaf(q1.y, kf[5], acc[l]);
            acc[l] = fmaf(q1.z, kf[6], acc[l]);
            acc[l] = fmaf(q1.w, kf[7], acc[l]);
        }
    }

    // ---- V chunk 0 (rows 0..27): issue BEFORE softmax to hide HBM latency ----
    float vb0[28];
#pragma unroll
    for (int i = 0; i < 28; ++i) vb0[i] = v[kbase + i * 512 + lane];

    // ---- softmax across lanes (s); P transposed into dead K buffer (fp32) ----
    float* pbuf = (float*)KL;
    float rdenom[7];
#pragma unroll
    for (int l = 0; l < 7; ++l) {
        float sc = acc[l] * m[l];
        if (lane >= 56) sc = -INFINITY;
        float mx = sc;
#pragma unroll
        for (int off = 32; off >= 1; off >>= 1)
            mx = fmaxf(mx, __shfl_xor(mx, off));
        const float p = __expf(sc - mx);   // pad lanes: exp(-inf)=0
        float sum = p;
#pragma unroll
        for (int off = 32; off >= 1; off >>= 1)
            sum += __shfl_xor(sum, off);
        pbuf[l * 64 + lane] = p;
        rdenom[l] = __builtin_amdgcn_rcpf(sum);
    }

    // ---- V chunk 1 (rows 28..55): issue before consuming chunk 0 ----
    float vb1[28];
#pragma unroll
    for (int i = 0; i < 28; ++i) vb1[i] = v[kbase + (28 + i) * 512 + lane];

    // ---- PV: lane = d ----
    float facc[7];
#pragma unroll
    for (int l = 0; l < 7; ++l) facc[l] = 0.0f;

#pragma unroll
    for (int s4 = 0; s4 < 7; ++s4) {
#pragma unroll
        for (int l = 0; l < 7; ++l) {
            const float4 p4 = *(const float4*)(&pbuf[l * 64 + s4 * 4]);  // broadcast
            facc[l] = fmaf(p4.x, vb0[s4 * 4 + 0], facc[l]);
            facc[l] = fmaf(p4.y, vb0[s4 * 4 + 1], facc[l]);
            facc[l] = fmaf(p4.z, vb0[s4 * 4 + 2], facc[l]);
            facc[l] = fmaf(p4.w, vb0[s4 * 4 + 3], facc[l]);
        }
    }
#pragma unroll
    for (int s4 = 0; s4 < 7; ++s4) {
#pragma unroll
        for (int l = 0; l < 7; ++l) {
            const float4 p4 = *(const float4*)(&pbuf[l * 64 + 28 + s4 * 4]);  // broadcast
            facc[l] = fmaf(p4.x, vb1[s4 * 4 + 0], facc[l]);
            facc[l] = fmaf(p4.y, vb1[s4 * 4 + 1], facc[l]);
            facc[l] = fmaf(p4.z, vb1[s4 * 4 + 2], facc[l]);
            facc[l] = fmaf(p4.w, vb1[s4 * 4 + 3], facc[l]);
        }
    }

    // ---- epilogue: deferred softmax normalization + coalesced store ----
#pragma unroll
    for (int l = 0; l < 7; ++l)
        out[qbase + l * 512 + lane] = facc[l] * rdenom[l];
}

extern "C" void kernel_launch(void* const* d_in, const int* in_sizes, int n_in,
                              void* d_out, int out_size, void* d_ws, size_t ws_size,
                              hipStream_t stream) {
    const float* q    = (const float*)d_in[0];
    const float* k    = (const float*)d_in[1];
    const float* v    = (const float*)d_in[2];
    const float* mask = (const float*)d_in[3];
    float* out        = (float*)d_out;

    const int B = in_sizes[0] / (7 * 8 * 64);        // 3200
    const int nstations = in_sizes[3] / (7 * 56);    // 50

    fullattn_kernel<<<dim3(B * 8), dim3(64), 0, stream>>>(q, k, v, mask, out, nstations);
}